// Round 11
// baseline (229.876 us; speedup 1.0000x reference)
//
#include <hip/hip_runtime.h>
#include <hip/hip_bf16.h>
#include <cstddef>

#define BIGV 10000000.0f
#define WPV  1.0f

#define BATCH 8
#define T1N 256
#define T2N 1024
#define CN 128
#define DN 1279          // T1+T2-1
#define NDT 20           // d-tiles of 64 rows per batch
#define NCOST (4 * BATCH * NDT)   // 640 cost blocks
#define CSTRIDE 68       // LDS row stride (64+4 floats)

// ---------------------------------------------------------------------------
// Fused producer-consumer kernel. Blocks [0,640): cost tiles, d-major order.
// Blocks [640,648): per-batch wave-synchronous DP consuming tiles as they
// complete (release: threadfence+atomicAdd; acquire: __hip_atomic_load).
// Co-residency by construction: 52 KB LDS -> 3 blk/CU x 256 CU = 768 >= 648,
// so producers always run even while consumers spin (no cooperative launch).
// ---------------------------------------------------------------------------
__global__ __launch_bounds__(256) void fused_kernel(const float* __restrict__ A,
                                                    const float* __restrict__ Bf,
                                                    const int* __restrict__ lenA,
                                                    const int* __restrict__ lenB,
                                                    float* __restrict__ sk,
                                                    int* __restrict__ cnt,
                                                    float* __restrict__ out) {
    __shared__ float As[64 * CSTRIDE];    // 17,408 B
    __shared__ float Bs[127 * CSTRIDE];   // 34,544 B  (total 51,952 B -> 3 blk/CU)

    const int bid = blockIdx.x;

    if (bid < NCOST) {
        // ---------------- producer: one 64x64 cost tile ----------------
        const int j0 = (bid & 3) * 64;
        const int b  = (bid >> 2) & 7;
        const int y  = bid >> 5;             // d-tile index, 0..19 (d-major)
        const int d0 = y * 64;
        const int tid = threadIdx.x;

        const int dEnd = lenA[b] + lenB[b] - 2;
        if (d0 > dEnd) {                     // rows never consumed pre-latch
            if (tid == 0)
                __hip_atomic_fetch_add(&cnt[b * NDT + y], 1,
                                       __ATOMIC_RELEASE, __HIP_MEMORY_SCOPE_AGENT);
            return;
        }

        const float* Ab = A  + (size_t)b * T1N * CN;
        const float* Bb = Bf + (size_t)b * T2N * CN;

        const int tj = tid & 15;
        const int td = tid >> 4;
        const int brow0 = td - tj + 63;      // local B row for dk==ji
        const int rbase = d0 - j0 - 63;      // global B row of local row 0

        float acc[4][4];
        #pragma unroll
        for (int i = 0; i < 4; ++i)
            #pragma unroll
            for (int j = 0; j < 4; ++j) acc[i][j] = 0.0f;

        for (int h = 0; h < 2; ++h) {
            const int ch0 = h * 64;
            #pragma unroll
            for (int i = 0; i < 4; ++i) {
                int idx = tid + i * 256;
                int row = idx >> 4;
                int c4  = (idx & 15) << 2;
                float4 f = *(const float4*)(Ab + (size_t)(j0 + row) * CN + ch0 + c4);
                *(float4*)&As[row * CSTRIDE + c4] = f;
            }
            #pragma unroll
            for (int i = 0; i < 8; ++i) {
                int idx = tid + i * 256;
                if (idx < 2032) {
                    int row = idx >> 4;
                    int c4  = (idx & 15) << 2;
                    int gr = rbase + row;
                    gr = gr < 0 ? 0 : (gr > T2N - 1 ? T2N - 1 : gr);
                    float4 f = *(const float4*)(Bb + (size_t)gr * CN + ch0 + c4);
                    *(float4*)&Bs[row * CSTRIDE + c4] = f;
                }
            }
            __syncthreads();

            for (int c = 0; c < 64; c += 4) {
                float4 a4[4], bv[7];
                #pragma unroll
                for (int ji = 0; ji < 4; ++ji)
                    a4[ji] = *(const float4*)&As[(tj + 16 * ji) * CSTRIDE + c];
                #pragma unroll
                for (int m = 0; m < 7; ++m)
                    bv[m] = *(const float4*)&Bs[(brow0 + 16 * (m - 3)) * CSTRIDE + c];
                #pragma unroll
                for (int dk = 0; dk < 4; ++dk) {
                    #pragma unroll
                    for (int ji = 0; ji < 4; ++ji) {
                        float4 aa = a4[ji];
                        float4 bb = bv[dk - ji + 3];
                        acc[dk][ji] += fabsf(aa.x - bb.x) + fabsf(aa.y - bb.y)
                                     + fabsf(aa.z - bb.z) + fabsf(aa.w - bb.w);
                    }
                }
            }
            __syncthreads();
        }

        #pragma unroll
        for (int dk = 0; dk < 4; ++dk) {
            int d = d0 + td + 16 * dk;
            if (d < DN) {
                size_t rowoff = ((size_t)b * DN + d) * T1N;
                #pragma unroll
                for (int ji = 0; ji < 4; ++ji) {
                    int j = j0 + tj + 16 * ji;
                    sk[rowoff + j] = acc[dk][ji] * (1.0f / 128.0f);
                }
            }
        }

        __threadfence();                     // publish this thread's stores
        __syncthreads();                     // all threads' fences done
        if (tid == 0)
            __hip_atomic_fetch_add(&cnt[b * NDT + y], 1,
                                   __ATOMIC_RELEASE, __HIP_MEMORY_SCOPE_AGENT);
        return;
    }

    // ---------------- consumer: wave-synchronous DP ----------------
    const int b = bid - NCOST;
    const int L = threadIdx.x;
    if (L >= 64) return;                     // wave 0 only (waves 1-3 exit)

    const int la = __builtin_amdgcn_readfirstlane(lenA[b]);
    const int lb = __builtin_amdgcn_readfirstlane(lenB[b]);
    const int dEnd = la + lb - 2;            // in [638, 1278]

    const float* skb = sk + (size_t)b * DN * T1N + L * 4;
    const int* cntb = cnt + b * NDT;

    float v1_0 = BIGV, v1_1 = BIGV, v1_2 = BIGV, v1_3 = BIGV;
    float v2_0 = BIGV, v2_1 = BIGV, v2_2 = BIGV, v2_3 = BIGV;
    float res0 = 0.0f, res1 = 0.0f, res2 = 0.0f, res3 = 0.0f;
    float p1_prev = (L == 0) ? 0.0f : BIGV;  // pcp0 boundary column

    int y_ck = 0;                            // next tile to verify ready

    float4 a0, a1, a2, a3, a4, a5, a6, a7, a8, a9, a10, a11, a12, a13, a14, a15;
    float4 b0, b1, b2, b3, b4, b5, b6, b7, b8, b9, b10, b11, b12, b13, b14, b15;
    float4 c0, c1, c2, c3, c4, c5, c6, c7, c8, c9, c10, c11, c12, c13, c14, c15;

#define WAIT_TILES(YN) do {                                                 \
        while (y_ck <= (YN)) {                                              \
            if (__hip_atomic_load(&cntb[y_ck], __ATOMIC_ACQUIRE,            \
                                  __HIP_MEMORY_SCOPE_AGENT) == 4) ++y_ck;   \
            else __builtin_amdgcn_s_sleep(2);                               \
        }                                                                   \
    } while (0)

#define LOAD_ONE(Q, ROW) do {                                               \
        int _rr = (ROW); _rr = _rr > DN - 1 ? DN - 1 : _rr;                 \
        Q = *(const float4*)(skb + (size_t)_rr * T1N);                      \
    } while (0)

#define LOAD_BLK(P, BASE) do {                                              \
        LOAD_ONE(P##0,  (BASE) + 0);  LOAD_ONE(P##1,  (BASE) + 1);          \
        LOAD_ONE(P##2,  (BASE) + 2);  LOAD_ONE(P##3,  (BASE) + 3);          \
        LOAD_ONE(P##4,  (BASE) + 4);  LOAD_ONE(P##5,  (BASE) + 5);          \
        LOAD_ONE(P##6,  (BASE) + 6);  LOAD_ONE(P##7,  (BASE) + 7);          \
        LOAD_ONE(P##8,  (BASE) + 8);  LOAD_ONE(P##9,  (BASE) + 9);          \
        LOAD_ONE(P##10, (BASE) + 10); LOAD_ONE(P##11, (BASE) + 11);         \
        LOAD_ONE(P##12, (BASE) + 12); LOAD_ONE(P##13, (BASE) + 13);         \
        LOAD_ONE(P##14, (BASE) + 14); LOAD_ONE(P##15, (BASE) + 15);         \
    } while (0)

#define SHFL_UP1(SRC)                                                       \
    __int_as_float(__builtin_amdgcn_update_dpp(                             \
        __float_as_int(BIGV), __float_as_int(SRC),                          \
        0x138 /* wave_shr:1 */, 0xF, 0xF, false))

#define DP_STEP(Q, STEPI) do {                                              \
        float4 c = (Q);                                                     \
        float p1 = SHFL_UP1(v1_3);                                          \
        float p2 = p1_prev;                                                 \
        float n0 = c.x + fminf(p2,   fminf(v1_0, p1)   + WPV);              \
        float n1 = c.y + fminf(v2_0, fminf(v1_1, v1_0) + WPV);              \
        float n2 = c.z + fminf(v2_1, fminf(v1_2, v1_1) + WPV);              \
        float n3 = c.w + fminf(v2_2, fminf(v1_3, v1_2) + WPV);              \
        if ((STEPI) == dEnd) { res0 = n0; res1 = n1; res2 = n2; res3 = n3; }\
        p1_prev = p1;                                                       \
        v2_0 = v1_0; v2_1 = v1_1; v2_2 = v1_2; v2_3 = v1_3;                 \
        v1_0 = n0;   v1_1 = n1;   v1_2 = n2;   v1_3 = n3;                   \
    } while (0)

#define DP_BLK(P, BASE) do {                                                \
        DP_STEP(P##0,  (BASE) + 0);  DP_STEP(P##1,  (BASE) + 1);            \
        DP_STEP(P##2,  (BASE) + 2);  DP_STEP(P##3,  (BASE) + 3);            \
        DP_STEP(P##4,  (BASE) + 4);  DP_STEP(P##5,  (BASE) + 5);            \
        DP_STEP(P##6,  (BASE) + 6);  DP_STEP(P##7,  (BASE) + 7);            \
        DP_STEP(P##8,  (BASE) + 8);  DP_STEP(P##9,  (BASE) + 9);            \
        DP_STEP(P##10, (BASE) + 10); DP_STEP(P##11, (BASE) + 11);           \
        DP_STEP(P##12, (BASE) + 12); DP_STEP(P##13, (BASE) + 13);           \
        DP_STEP(P##14, (BASE) + 14); DP_STEP(P##15, (BASE) + 15);           \
    } while (0)

#define FENCE() __builtin_amdgcn_sched_barrier(0)

    WAIT_TILES(0);                           // rows 0..47 live in tile 0
    LOAD_BLK(a, 0);
    LOAD_BLK(b, 16);
    LOAD_BLK(c, 32);

    const int nsb = dEnd / 48 + 1;
    for (int sb = 0; sb < nsb; ++sb) {
        const int base = sb * 48;
        // this superblock issues loads for rows base+48 .. base+143
        int hi = base + 143; hi = hi > DN - 1 ? DN - 1 : hi;
        WAIT_TILES(hi >> 6);
        FENCE();
        DP_BLK(a, base);
        FENCE();
        LOAD_BLK(a, base + 48);
        FENCE();
        DP_BLK(b, base + 16);
        FENCE();
        LOAD_BLK(b, base + 64);
        FENCE();
        DP_BLK(c, base + 32);
        FENCE();
        LOAD_BLK(c, base + 80);
        FENCE();
    }

    // loss_i = row dEnd at column la -> t = la-1, lane (la-1)>>2, slot (la-1)&3
    const int tcap = la - 1;
    if (L == (tcap >> 2)) {
        const int k = tcap & 3;
        float r = res0;
        if (k == 1) r = res1;
        else if (k == 2) r = res2;
        else if (k == 3) r = res3;
        atomicAdd(out, r);                   // out zeroed via hipMemsetAsync
    }
#undef FENCE
#undef DP_BLK
#undef DP_STEP
#undef SHFL_UP1
#undef LOAD_BLK
#undef LOAD_ONE
#undef WAIT_TILES
}

extern "C" void kernel_launch(void* const* d_in, const int* in_sizes, int n_in,
                              void* d_out, int out_size, void* d_ws, size_t ws_size,
                              hipStream_t stream) {
    const float* feaA = (const float*)d_in[0];
    const int*   lenA = (const int*)d_in[1];
    const float* feaB = (const float*)d_in[2];
    const int*   lenB = (const int*)d_in[3];

    float* sk = (float*)d_ws;                            // 8*1279*256*4 = 10,477,568 B
    int* cnt = (int*)((char*)d_ws + (size_t)BATCH * DN * T1N * sizeof(float)); // 160 ints

    hipMemsetAsync(cnt, 0, BATCH * NDT * sizeof(int), stream);
    hipMemsetAsync(d_out, 0, sizeof(float), stream);
    fused_kernel<<<NCOST + BATCH, 256, 0, stream>>>(feaA, feaB, lenA, lenB,
                                                    sk, cnt, (float*)d_out);
}

// Round 12
// 172.235 us; speedup vs baseline: 1.3347x; 1.3347x over previous
//
#include <hip/hip_runtime.h>
#include <hip/hip_bf16.h>
#include <cstddef>

#define BIGV 10000000.0f
#define WPV  1.0f

#define BATCH 8
#define T1N 256
#define T2N 1024
#define CN 128
#define DN 1279          // T1+T2-1
#define CSTRIDE 68       // cost LDS row stride (64+4 floats)

#define RPB 16           // rows per ring block (16 KB)
#define NSLOT 3          // ring slots
#define SLOT_BYTES (RPB * 1024)

// ---------------------------------------------------------------------------
// Kernel 1: skewed cost (R10 64x64 version, unchanged)
// ---------------------------------------------------------------------------
__global__ __launch_bounds__(256) void cost_kernel(const float* __restrict__ A,
                                                   const float* __restrict__ Bf,
                                                   const int* __restrict__ lenA,
                                                   const int* __restrict__ lenB,
                                                   float* __restrict__ sk) {
    __shared__ float As[64 * CSTRIDE];    // 17,408 B
    __shared__ float Bs[127 * CSTRIDE];   // 34,544 B

    const int b  = blockIdx.z;
    const int d0 = blockIdx.y * 64;
    const int j0 = blockIdx.x * 64;
    const int tid = threadIdx.x;

    const int dEnd = lenA[b] + lenB[b] - 2;
    if (d0 > dEnd) return;               // rows never consumed pre-latch

    const float* Ab = A  + (size_t)b * T1N * CN;
    const float* Bb = Bf + (size_t)b * T2N * CN;

    const int tj = tid & 15;
    const int td = tid >> 4;
    const int brow0 = td - tj + 63;
    const int rbase = d0 - j0 - 63;

    float acc[4][4];
    #pragma unroll
    for (int i = 0; i < 4; ++i)
        #pragma unroll
        for (int j = 0; j < 4; ++j) acc[i][j] = 0.0f;

    for (int h = 0; h < 2; ++h) {
        const int ch0 = h * 64;
        #pragma unroll
        for (int i = 0; i < 4; ++i) {
            int idx = tid + i * 256;
            int row = idx >> 4;
            int c4  = (idx & 15) << 2;
            float4 f = *(const float4*)(Ab + (size_t)(j0 + row) * CN + ch0 + c4);
            *(float4*)&As[row * CSTRIDE + c4] = f;
        }
        #pragma unroll
        for (int i = 0; i < 8; ++i) {
            int idx = tid + i * 256;
            if (idx < 2032) {
                int row = idx >> 4;
                int c4  = (idx & 15) << 2;
                int gr = rbase + row;
                gr = gr < 0 ? 0 : (gr > T2N - 1 ? T2N - 1 : gr);
                float4 f = *(const float4*)(Bb + (size_t)gr * CN + ch0 + c4);
                *(float4*)&Bs[row * CSTRIDE + c4] = f;
            }
        }
        __syncthreads();

        for (int c = 0; c < 64; c += 4) {
            float4 a4[4], bv[7];
            #pragma unroll
            for (int ji = 0; ji < 4; ++ji)
                a4[ji] = *(const float4*)&As[(tj + 16 * ji) * CSTRIDE + c];
            #pragma unroll
            for (int m = 0; m < 7; ++m)
                bv[m] = *(const float4*)&Bs[(brow0 + 16 * (m - 3)) * CSTRIDE + c];
            #pragma unroll
            for (int dk = 0; dk < 4; ++dk) {
                #pragma unroll
                for (int ji = 0; ji < 4; ++ji) {
                    float4 aa = a4[ji];
                    float4 bb = bv[dk - ji + 3];
                    acc[dk][ji] += fabsf(aa.x - bb.x) + fabsf(aa.y - bb.y)
                                 + fabsf(aa.z - bb.z) + fabsf(aa.w - bb.w);
                }
            }
        }
        __syncthreads();
    }

    #pragma unroll
    for (int dk = 0; dk < 4; ++dk) {
        int d = d0 + td + 16 * dk;
        if (d < DN) {
            size_t rowoff = ((size_t)b * DN + d) * T1N;
            #pragma unroll
            for (int ji = 0; ji < 4; ++ji) {
                int j = j0 + tj + 16 * ji;
                sk[rowoff + j] = acc[dk][ji] * (1.0f / 128.0f);
            }
        }
    }
}

// ---------------------------------------------------------------------------
// Kernel 2: dp with intra-block producer/consumer waves.
// R11 post-mortem: every register-ring scheme was undone by LLVM load
// sinking (VGPR stuck at 108) -> consumer wave kept eating raw load latency.
// Now wave 1 DMAs cost rows into a 3-slot LDS ring via global_load_lds
// (lane L's 16B -> slot + r*1024 + L*16, exactly the consumer layout);
// pacing by s_waitcnt vmcnt(16) on the PRODUCER wave only. Wave 0 runs the
// DPP step from ds_read_b128 — zero global loads, zero vmcnt on the chain.
// ---------------------------------------------------------------------------
__global__ __launch_bounds__(128, 1) void dp_wave_kernel(const float* __restrict__ sk,
                                                         const int* __restrict__ lenA,
                                                         const int* __restrict__ lenB,
                                                         float* __restrict__ partials) {
    __shared__ char ring[NSLOT * SLOT_BYTES];   // 48 KB
    __shared__ int prod_cnt;                     // blocks ready
    __shared__ int cons_cnt;                     // blocks consumed

    const int b = blockIdx.x;
    if (threadIdx.x == 0) { prod_cnt = 0; cons_cnt = 0; }
    __syncthreads();

    const int wave = threadIdx.x >> 6;
    const int L = threadIdx.x & 63;

    const int la = __builtin_amdgcn_readfirstlane(lenA[b]);
    const int lb = __builtin_amdgcn_readfirstlane(lenB[b]);
    const int dEnd = la + lb - 2;                // in [638, 1278]
    const int nblk = dEnd / RPB + 1;             // 16-row blocks covering dEnd

    if (wave == 1) {
        // ---------------- producer: DMA rows into the LDS ring ----------------
        const float* skbp = sk + (size_t)b * DN * T1N + (L << 2);
        for (int k = 0; k < nblk; ++k) {
            if (k >= NSLOT) {
                while (__hip_atomic_load(&cons_cnt, __ATOMIC_ACQUIRE,
                                         __HIP_MEMORY_SCOPE_WORKGROUP) < k - (NSLOT - 1))
                    __builtin_amdgcn_s_sleep(1);
            }
            char* slot = ring + (k % NSLOT) * SLOT_BYTES;
            const int r0 = k * RPB;
            #pragma unroll
            for (int r = 0; r < RPB; ++r) {
                int row = r0 + r; row = row > DN - 1 ? DN - 1 : row;
                __builtin_amdgcn_global_load_lds(
                    (const __attribute__((address_space(1))) void*)(skbp + (size_t)row * T1N),
                    (__attribute__((address_space(3))) void*)(slot + (r << 10)),
                    16, 0, 0);
            }
            // <=16 outstanding -> block k-1 (and older) fully landed
            asm volatile("s_waitcnt vmcnt(16)" ::: "memory");
            if (L == 0)
                __hip_atomic_store(&prod_cnt, k, __ATOMIC_RELEASE,
                                   __HIP_MEMORY_SCOPE_WORKGROUP);
        }
        asm volatile("s_waitcnt vmcnt(0)" ::: "memory");
        if (L == 0)
            __hip_atomic_store(&prod_cnt, nblk, __ATOMIC_RELEASE,
                               __HIP_MEMORY_SCOPE_WORKGROUP);
        return;
    }

    // ---------------- consumer: pure-VALU DP off the LDS ring ----------------
    float v1_0 = BIGV, v1_1 = BIGV, v1_2 = BIGV, v1_3 = BIGV;
    float v2_0 = BIGV, v2_1 = BIGV, v2_2 = BIGV, v2_3 = BIGV;
    float res0 = 0.0f, res1 = 0.0f, res2 = 0.0f, res3 = 0.0f;
    float p1_prev = (L == 0) ? 0.0f : BIGV;      // pcp0 boundary column

#define SHFL_UP1(SRC)                                                       \
    __int_as_float(__builtin_amdgcn_update_dpp(                             \
        __float_as_int(BIGV), __float_as_int(SRC),                          \
        0x138 /* wave_shr:1 */, 0xF, 0xF, false))

#define DP_STEP(C4, STEPI) do {                                             \
        float4 c = (C4);                                                    \
        float p1 = SHFL_UP1(v1_3);                                          \
        float p2 = p1_prev;                                                 \
        float n0 = c.x + fminf(p2,   fminf(v1_0, p1)   + WPV);              \
        float n1 = c.y + fminf(v2_0, fminf(v1_1, v1_0) + WPV);              \
        float n2 = c.z + fminf(v2_1, fminf(v1_2, v1_1) + WPV);              \
        float n3 = c.w + fminf(v2_2, fminf(v1_3, v1_2) + WPV);              \
        if ((STEPI) == dEnd) { res0 = n0; res1 = n1; res2 = n2; res3 = n3; }\
        p1_prev = p1;                                                       \
        v2_0 = v1_0; v2_1 = v1_1; v2_2 = v1_2; v2_3 = v1_3;                 \
        v1_0 = n0;   v1_1 = n1;   v1_2 = n2;   v1_3 = n3;                   \
    } while (0)

    for (int k = 0; k < nblk; ++k) {
        while (__hip_atomic_load(&prod_cnt, __ATOMIC_ACQUIRE,
                                 __HIP_MEMORY_SCOPE_WORKGROUP) < k + 1)
            __builtin_amdgcn_s_sleep(1);
        const char* slot = ring + (k % NSLOT) * SLOT_BYTES;
        const float4* rp = (const float4*)(slot + (L << 4));
        const int s0 = k * RPB;
        #pragma unroll
        for (int r = 0; r < RPB; ++r) {
            float4 cc = rp[r * 64];              // ds_read_b128, imm offset r*1024
            DP_STEP(cc, s0 + r);
        }
        if (L == 0)
            __hip_atomic_store(&cons_cnt, k + 1, __ATOMIC_RELEASE,
                               __HIP_MEMORY_SCOPE_WORKGROUP);
    }

    // loss_i = row dEnd at column la -> t = la-1, lane (la-1)>>2, slot (la-1)&3
    const int tcap = la - 1;
    if (L == (tcap >> 2)) {
        const int k = tcap & 3;
        float r = res0;
        if (k == 1) r = res1;
        else if (k == 2) r = res2;
        else if (k == 3) r = res3;
        partials[b] = r;
    }
#undef DP_STEP
#undef SHFL_UP1
}

// ---------------------------------------------------------------------------
// Kernel 3: sum the 8 per-batch losses into d_out[0]
// ---------------------------------------------------------------------------
__global__ void reduce_kernel(const float* __restrict__ partials,
                              float* __restrict__ out) {
    if (threadIdx.x == 0) {
        float s = 0.0f;
        for (int i = 0; i < BATCH; ++i) s += partials[i];
        out[0] = s;
    }
}

extern "C" void kernel_launch(void* const* d_in, const int* in_sizes, int n_in,
                              void* d_out, int out_size, void* d_ws, size_t ws_size,
                              hipStream_t stream) {
    const float* feaA = (const float*)d_in[0];
    const int*   lenA = (const int*)d_in[1];
    const float* feaB = (const float*)d_in[2];
    const int*   lenB = (const int*)d_in[3];

    float* sk = (float*)d_ws;                                   // 8*1279*256*4 B
    float* partials = (float*)((char*)d_ws + (size_t)BATCH * DN * T1N * sizeof(float));

    cost_kernel<<<dim3(T1N / 64, (DN + 63) / 64, BATCH), 256, 0, stream>>>(feaA, feaB, lenA, lenB, sk);
    dp_wave_kernel<<<BATCH, 128, 0, stream>>>(sk, lenA, lenB, partials);
    reduce_kernel<<<1, 64, 0, stream>>>(partials, (float*)d_out);
}

// Round 13
// 166.346 us; speedup vs baseline: 1.3819x; 1.0354x over previous
//
#include <hip/hip_runtime.h>
#include <hip/hip_bf16.h>
#include <cstddef>

#define BIGV 10000000.0f
#define WPV  1.0f

#define BATCH 8
#define T1N 256
#define T2N 1024
#define CN 128
#define DN 1279          // T1+T2-1
#define CSTRIDE 68       // cost LDS row stride (64+4 floats)

#define RPB 16           // rows per ring block (16 KB)
#define NSLOT 3          // ring slots
#define SLOT_BYTES (RPB * 1024)

// ---------------------------------------------------------------------------
// Kernel 1: skewed cost (R10 64x64 version, unchanged — counters next round)
// ---------------------------------------------------------------------------
__global__ __launch_bounds__(256) void cost_kernel(const float* __restrict__ A,
                                                   const float* __restrict__ Bf,
                                                   const int* __restrict__ lenA,
                                                   const int* __restrict__ lenB,
                                                   float* __restrict__ sk) {
    __shared__ float As[64 * CSTRIDE];    // 17,408 B
    __shared__ float Bs[127 * CSTRIDE];   // 34,544 B

    const int b  = blockIdx.z;
    const int d0 = blockIdx.y * 64;
    const int j0 = blockIdx.x * 64;
    const int tid = threadIdx.x;

    const int dEnd = lenA[b] + lenB[b] - 2;
    if (d0 > dEnd) return;               // rows never consumed pre-latch

    const float* Ab = A  + (size_t)b * T1N * CN;
    const float* Bb = Bf + (size_t)b * T2N * CN;

    const int tj = tid & 15;
    const int td = tid >> 4;
    const int brow0 = td - tj + 63;
    const int rbase = d0 - j0 - 63;

    float acc[4][4];
    #pragma unroll
    for (int i = 0; i < 4; ++i)
        #pragma unroll
        for (int j = 0; j < 4; ++j) acc[i][j] = 0.0f;

    for (int h = 0; h < 2; ++h) {
        const int ch0 = h * 64;
        #pragma unroll
        for (int i = 0; i < 4; ++i) {
            int idx = tid + i * 256;
            int row = idx >> 4;
            int c4  = (idx & 15) << 2;
            float4 f = *(const float4*)(Ab + (size_t)(j0 + row) * CN + ch0 + c4);
            *(float4*)&As[row * CSTRIDE + c4] = f;
        }
        #pragma unroll
        for (int i = 0; i < 8; ++i) {
            int idx = tid + i * 256;
            if (idx < 2032) {
                int row = idx >> 4;
                int c4  = (idx & 15) << 2;
                int gr = rbase + row;
                gr = gr < 0 ? 0 : (gr > T2N - 1 ? T2N - 1 : gr);
                float4 f = *(const float4*)(Bb + (size_t)gr * CN + ch0 + c4);
                *(float4*)&Bs[row * CSTRIDE + c4] = f;
            }
        }
        __syncthreads();

        for (int c = 0; c < 64; c += 4) {
            float4 a4[4], bv[7];
            #pragma unroll
            for (int ji = 0; ji < 4; ++ji)
                a4[ji] = *(const float4*)&As[(tj + 16 * ji) * CSTRIDE + c];
            #pragma unroll
            for (int m = 0; m < 7; ++m)
                bv[m] = *(const float4*)&Bs[(brow0 + 16 * (m - 3)) * CSTRIDE + c];
            #pragma unroll
            for (int dk = 0; dk < 4; ++dk) {
                #pragma unroll
                for (int ji = 0; ji < 4; ++ji) {
                    float4 aa = a4[ji];
                    float4 bb = bv[dk - ji + 3];
                    acc[dk][ji] += fabsf(aa.x - bb.x) + fabsf(aa.y - bb.y)
                                 + fabsf(aa.z - bb.z) + fabsf(aa.w - bb.w);
                }
            }
        }
        __syncthreads();
    }

    #pragma unroll
    for (int dk = 0; dk < 4; ++dk) {
        int d = d0 + td + 16 * dk;
        if (d < DN) {
            size_t rowoff = ((size_t)b * DN + d) * T1N;
            #pragma unroll
            for (int ji = 0; ji < 4; ++ji) {
                int j = j0 + tj + 16 * ji;
                sk[rowoff + j] = acc[dk][ji] * (1.0f / 128.0f);
            }
        }
    }
}

// ---------------------------------------------------------------------------
// Kernel 2: dp, producer/consumer waves (R12) + R13 change: the consumer
// BATCHES its 16 ds_read_b128 into named registers at block top (fenced by
// sched_barrier so they can't sink into the serial chain) — one staggered
// lgkm wait per block instead of one exposed LDS latency per step.
// Result is atomicAdd'ed into d_out directly (reduce kernel dropped).
// ---------------------------------------------------------------------------
__global__ __launch_bounds__(128, 1) void dp_wave_kernel(const float* __restrict__ sk,
                                                         const int* __restrict__ lenA,
                                                         const int* __restrict__ lenB,
                                                         float* __restrict__ out) {
    __shared__ char ring[NSLOT * SLOT_BYTES];   // 48 KB
    __shared__ int prod_cnt;
    __shared__ int cons_cnt;

    const int b = blockIdx.x;
    if (threadIdx.x == 0) { prod_cnt = 0; cons_cnt = 0; }
    __syncthreads();

    const int wave = threadIdx.x >> 6;
    const int L = threadIdx.x & 63;

    const int la = __builtin_amdgcn_readfirstlane(lenA[b]);
    const int lb = __builtin_amdgcn_readfirstlane(lenB[b]);
    const int dEnd = la + lb - 2;                // in [638, 1278]
    const int nblk = dEnd / RPB + 1;

    if (wave == 1) {
        // ---------------- producer: DMA rows into the LDS ring ----------------
        const float* skbp = sk + (size_t)b * DN * T1N + (L << 2);
        for (int k = 0; k < nblk; ++k) {
            if (k >= NSLOT) {
                while (__hip_atomic_load(&cons_cnt, __ATOMIC_ACQUIRE,
                                         __HIP_MEMORY_SCOPE_WORKGROUP) < k - (NSLOT - 1))
                    __builtin_amdgcn_s_sleep(1);
            }
            char* slot = ring + (k % NSLOT) * SLOT_BYTES;
            const int r0 = k * RPB;
            #pragma unroll
            for (int r = 0; r < RPB; ++r) {
                int row = r0 + r; row = row > DN - 1 ? DN - 1 : row;
                __builtin_amdgcn_global_load_lds(
                    (const __attribute__((address_space(1))) void*)(skbp + (size_t)row * T1N),
                    (__attribute__((address_space(3))) void*)(slot + (r << 10)),
                    16, 0, 0);
            }
            // <=16 outstanding -> block k-1 (and older) fully landed
            asm volatile("s_waitcnt vmcnt(16)" ::: "memory");
            if (L == 0)
                __hip_atomic_store(&prod_cnt, k, __ATOMIC_RELEASE,
                                   __HIP_MEMORY_SCOPE_WORKGROUP);
        }
        asm volatile("s_waitcnt vmcnt(0)" ::: "memory");
        if (L == 0)
            __hip_atomic_store(&prod_cnt, nblk, __ATOMIC_RELEASE,
                               __HIP_MEMORY_SCOPE_WORKGROUP);
        return;
    }

    // ---------------- consumer: pure-VALU DP off the LDS ring ----------------
    float v1_0 = BIGV, v1_1 = BIGV, v1_2 = BIGV, v1_3 = BIGV;
    float v2_0 = BIGV, v2_1 = BIGV, v2_2 = BIGV, v2_3 = BIGV;
    float res0 = 0.0f, res1 = 0.0f, res2 = 0.0f, res3 = 0.0f;
    float p1_prev = (L == 0) ? 0.0f : BIGV;      // pcp0 boundary column

#define SHFL_UP1(SRC)                                                       \
    __int_as_float(__builtin_amdgcn_update_dpp(                             \
        __float_as_int(BIGV), __float_as_int(SRC),                          \
        0x138 /* wave_shr:1 */, 0xF, 0xF, false))

#define DP_STEP(C4, STEPI) do {                                             \
        float4 c = (C4);                                                    \
        float p1 = SHFL_UP1(v1_3);                                          \
        float p2 = p1_prev;                                                 \
        float n0 = c.x + fminf(p2,   fminf(v1_0, p1)   + WPV);              \
        float n1 = c.y + fminf(v2_0, fminf(v1_1, v1_0) + WPV);              \
        float n2 = c.z + fminf(v2_1, fminf(v1_2, v1_1) + WPV);              \
        float n3 = c.w + fminf(v2_2, fminf(v1_3, v1_2) + WPV);              \
        if ((STEPI) == dEnd) { res0 = n0; res1 = n1; res2 = n2; res3 = n3; }\
        p1_prev = p1;                                                       \
        v2_0 = v1_0; v2_1 = v1_1; v2_2 = v1_2; v2_3 = v1_3;                 \
        v1_0 = n0;   v1_1 = n1;   v1_2 = n2;   v1_3 = n3;                   \
    } while (0)

    for (int k = 0; k < nblk; ++k) {
        while (__hip_atomic_load(&prod_cnt, __ATOMIC_ACQUIRE,
                                 __HIP_MEMORY_SCOPE_WORKGROUP) < k + 1)
            __builtin_amdgcn_s_sleep(1);
        const char* slot = ring + (k % NSLOT) * SLOT_BYTES;
        const float4* rp = (const float4*)(slot + (L << 4));
        const int s0 = k * RPB;

        // batch all 16 LDS reads (named regs) before entering the chain
        float4 c0  = rp[0 * 64],  c1  = rp[1 * 64],  c2  = rp[2 * 64],  c3  = rp[3 * 64];
        float4 c4_ = rp[4 * 64],  c5  = rp[5 * 64],  c6  = rp[6 * 64],  c7  = rp[7 * 64];
        float4 c8  = rp[8 * 64],  c9  = rp[9 * 64],  c10 = rp[10 * 64], c11 = rp[11 * 64];
        float4 c12 = rp[12 * 64], c13 = rp[13 * 64], c14 = rp[14 * 64], c15 = rp[15 * 64];
        __builtin_amdgcn_sched_barrier(0);   // keep reads batched above the chain

        DP_STEP(c0,  s0 + 0);  DP_STEP(c1,  s0 + 1);
        DP_STEP(c2,  s0 + 2);  DP_STEP(c3,  s0 + 3);
        DP_STEP(c4_, s0 + 4);  DP_STEP(c5,  s0 + 5);
        DP_STEP(c6,  s0 + 6);  DP_STEP(c7,  s0 + 7);
        DP_STEP(c8,  s0 + 8);  DP_STEP(c9,  s0 + 9);
        DP_STEP(c10, s0 + 10); DP_STEP(c11, s0 + 11);
        DP_STEP(c12, s0 + 12); DP_STEP(c13, s0 + 13);
        DP_STEP(c14, s0 + 14); DP_STEP(c15, s0 + 15);

        if (L == 0)
            __hip_atomic_store(&cons_cnt, k + 1, __ATOMIC_RELEASE,
                               __HIP_MEMORY_SCOPE_WORKGROUP);
    }

    // loss_i = row dEnd at column la -> t = la-1, lane (la-1)>>2, slot (la-1)&3
    const int tcap = la - 1;
    if (L == (tcap >> 2)) {
        const int k = tcap & 3;
        float r = res0;
        if (k == 1) r = res1;
        else if (k == 2) r = res2;
        else if (k == 3) r = res3;
        atomicAdd(out, r);                   // d_out zeroed via hipMemsetAsync
    }
#undef DP_STEP
#undef SHFL_UP1
}

extern "C" void kernel_launch(void* const* d_in, const int* in_sizes, int n_in,
                              void* d_out, int out_size, void* d_ws, size_t ws_size,
                              hipStream_t stream) {
    const float* feaA = (const float*)d_in[0];
    const int*   lenA = (const int*)d_in[1];
    const float* feaB = (const float*)d_in[2];
    const int*   lenB = (const int*)d_in[3];

    float* sk = (float*)d_ws;                                   // 8*1279*256*4 B

    hipMemsetAsync(d_out, 0, sizeof(float), stream);
    cost_kernel<<<dim3(T1N / 64, (DN + 63) / 64, BATCH), 256, 0, stream>>>(feaA, feaB, lenA, lenB, sk);
    dp_wave_kernel<<<BATCH, 128, 0, stream>>>(sk, lenA, lenB, (float*)d_out);
}

// Round 14
// 160.284 us; speedup vs baseline: 1.4342x; 1.0378x over previous
//
#include <hip/hip_runtime.h>
#include <hip/hip_bf16.h>
#include <cstddef>

#define BIGV 10000000.0f
#define WPV  1.0f

#define BATCH 8
#define T1N 256
#define T2N 1024
#define CN 128
#define DN 1279          // T1+T2-1

#define RPB 16           // rows per ring block (16 KB)
#define NSLOT 3          // ring slots
#define SLOT_BYTES (RPB * 1024)

// ---------------------------------------------------------------------------
// Kernel 1: skewed cost, R14: XOR-swizzled LDS (stride 64, col' = (cq+row)&15).
// Old CSTRIDE=68 = 4 mod 32 banks -> As reads ~4-way, Bs reads ~2-3x
// serialized (19 distinct rows over 8 b128 bank-slots). Swizzle spreads
// consecutive rows across slots: A-reads broadcast+2-way (free, m136),
// B-reads ~1.2x. LDS: As 16 KB + Bs 32.5 KB = 48.9 KB -> 3 blocks/CU.
// ---------------------------------------------------------------------------
__global__ __launch_bounds__(256) void cost_kernel(const float* __restrict__ A,
                                                   const float* __restrict__ Bf,
                                                   const int* __restrict__ lenA,
                                                   const int* __restrict__ lenB,
                                                   float* __restrict__ sk) {
    __shared__ float As[64 * 64];     // 16,384 B
    __shared__ float Bs[127 * 64];    // 32,512 B

    const int b  = blockIdx.z;
    const int d0 = blockIdx.y * 64;
    const int j0 = blockIdx.x * 64;
    const int tid = threadIdx.x;

    const int dEnd = lenA[b] + lenB[b] - 2;
    if (d0 > dEnd) return;            // rows never consumed pre-latch

    const float* Ab = A  + (size_t)b * T1N * CN;
    const float* Bb = Bf + (size_t)b * T2N * CN;

    const int tj = tid & 15;
    const int td = tid >> 4;
    const int brow0 = td - tj + 63;   // in [48,66]
    const int rbase = d0 - j0 - 63;

    float acc[4][4];
    #pragma unroll
    for (int i = 0; i < 4; ++i)
        #pragma unroll
        for (int j = 0; j < 4; ++j) acc[i][j] = 0.0f;

    // swizzled dword offset for (row, cq) where cq = float4 column 0..15
#define SW(row, cq) (((row) << 6) + ((((cq) + (row)) & 15) << 2))

    for (int h = 0; h < 2; ++h) {
        const int ch0 = h * 64;
        #pragma unroll
        for (int i = 0; i < 4; ++i) {
            int idx = tid + i * 256;
            int row = idx >> 4;
            int cq  = idx & 15;
            float4 f = *(const float4*)(Ab + (size_t)(j0 + row) * CN + ch0 + (cq << 2));
            *(float4*)&As[SW(row, cq)] = f;
        }
        #pragma unroll
        for (int i = 0; i < 8; ++i) {
            int idx = tid + i * 256;
            if (idx < 2032) {                 // 127 rows x 16
                int row = idx >> 4;
                int cq  = idx & 15;
                int gr = rbase + row;
                gr = gr < 0 ? 0 : (gr > T2N - 1 ? T2N - 1 : gr);
                float4 f = *(const float4*)(Bb + (size_t)gr * CN + ch0 + (cq << 2));
                *(float4*)&Bs[SW(row, cq)] = f;
            }
        }
        __syncthreads();

        for (int cq = 0; cq < 16; ++cq) {
            float4 a4[4], bv[7];
            #pragma unroll
            for (int ji = 0; ji < 4; ++ji) {
                int row = tj + 16 * ji;
                a4[ji] = *(const float4*)&As[SW(row, cq)];
            }
            #pragma unroll
            for (int m = 0; m < 7; ++m) {
                int row = brow0 + 16 * (m - 3);
                bv[m] = *(const float4*)&Bs[SW(row, cq)];
            }
            #pragma unroll
            for (int dk = 0; dk < 4; ++dk) {
                #pragma unroll
                for (int ji = 0; ji < 4; ++ji) {
                    float4 aa = a4[ji];
                    float4 bb = bv[dk - ji + 3];
                    acc[dk][ji] += fabsf(aa.x - bb.x) + fabsf(aa.y - bb.y)
                                 + fabsf(aa.z - bb.z) + fabsf(aa.w - bb.w);
                }
            }
        }
        __syncthreads();
    }
#undef SW

    #pragma unroll
    for (int dk = 0; dk < 4; ++dk) {
        int d = d0 + td + 16 * dk;
        if (d < DN) {
            size_t rowoff = ((size_t)b * DN + d) * T1N;
            #pragma unroll
            for (int ji = 0; ji < 4; ++ji) {
                int j = j0 + tj + 16 * ji;
                sk[rowoff + j] = acc[dk][ji] * (1.0f / 128.0f);
            }
        }
    }
}

// ---------------------------------------------------------------------------
// Kernel 2: dp, producer/consumer waves. R14: per-step dEnd latch removed —
// full blocks run unguarded; only the final block (k = dEnd>>4) guards its
// state updates with r <= rem; result read directly from v1_k afterwards.
// ---------------------------------------------------------------------------
__global__ __launch_bounds__(128, 1) void dp_wave_kernel(const float* __restrict__ sk,
                                                         const int* __restrict__ lenA,
                                                         const int* __restrict__ lenB,
                                                         float* __restrict__ out) {
    __shared__ char ring[NSLOT * SLOT_BYTES];   // 48 KB
    __shared__ int prod_cnt;
    __shared__ int cons_cnt;

    const int b = blockIdx.x;
    if (threadIdx.x == 0) { prod_cnt = 0; cons_cnt = 0; }
    __syncthreads();

    const int wave = threadIdx.x >> 6;
    const int L = threadIdx.x & 63;

    const int la = __builtin_amdgcn_readfirstlane(lenA[b]);
    const int lb = __builtin_amdgcn_readfirstlane(lenB[b]);
    const int dEnd = la + lb - 2;                // in [638, 1278]
    const int kLast = dEnd >> 4;                 // final block index
    const int nblk = kLast + 1;

    if (wave == 1) {
        // ---------------- producer: DMA rows into the LDS ring ----------------
        const float* skbp = sk + (size_t)b * DN * T1N + (L << 2);
        for (int k = 0; k < nblk; ++k) {
            if (k >= NSLOT) {
                while (__hip_atomic_load(&cons_cnt, __ATOMIC_ACQUIRE,
                                         __HIP_MEMORY_SCOPE_WORKGROUP) < k - (NSLOT - 1))
                    __builtin_amdgcn_s_sleep(1);
            }
            char* slot = ring + (k % NSLOT) * SLOT_BYTES;
            const int r0 = k * RPB;
            #pragma unroll
            for (int r = 0; r < RPB; ++r) {
                int row = r0 + r; row = row > DN - 1 ? DN - 1 : row;
                __builtin_amdgcn_global_load_lds(
                    (const __attribute__((address_space(1))) void*)(skbp + (size_t)row * T1N),
                    (__attribute__((address_space(3))) void*)(slot + (r << 10)),
                    16, 0, 0);
            }
            // <=16 outstanding -> block k-1 (and older) fully landed
            asm volatile("s_waitcnt vmcnt(16)" ::: "memory");
            if (L == 0)
                __hip_atomic_store(&prod_cnt, k, __ATOMIC_RELEASE,
                                   __HIP_MEMORY_SCOPE_WORKGROUP);
        }
        asm volatile("s_waitcnt vmcnt(0)" ::: "memory");
        if (L == 0)
            __hip_atomic_store(&prod_cnt, nblk, __ATOMIC_RELEASE,
                               __HIP_MEMORY_SCOPE_WORKGROUP);
        return;
    }

    // ---------------- consumer: pure-VALU DP off the LDS ring ----------------
    float v1_0 = BIGV, v1_1 = BIGV, v1_2 = BIGV, v1_3 = BIGV;
    float v2_0 = BIGV, v2_1 = BIGV, v2_2 = BIGV, v2_3 = BIGV;
    float p1_prev = (L == 0) ? 0.0f : BIGV;      // pcp0 boundary column

#define SHFL_UP1(SRC)                                                       \
    __int_as_float(__builtin_amdgcn_update_dpp(                             \
        __float_as_int(BIGV), __float_as_int(SRC),                          \
        0x138 /* wave_shr:1 */, 0xF, 0xF, false))

#define DP_STEP(C4) do {                                                    \
        float4 c = (C4);                                                    \
        float p1 = SHFL_UP1(v1_3);                                          \
        float p2 = p1_prev;                                                 \
        float n0 = c.x + fminf(p2,   fminf(v1_0, p1)   + WPV);              \
        float n1 = c.y + fminf(v2_0, fminf(v1_1, v1_0) + WPV);              \
        float n2 = c.z + fminf(v2_1, fminf(v1_2, v1_1) + WPV);              \
        float n3 = c.w + fminf(v2_2, fminf(v1_3, v1_2) + WPV);              \
        p1_prev = p1;                                                       \
        v2_0 = v1_0; v2_1 = v1_1; v2_2 = v1_2; v2_3 = v1_3;                 \
        v1_0 = n0;   v1_1 = n1;   v1_2 = n2;   v1_3 = n3;                   \
    } while (0)

    // guarded step for the final block: state advances only while r <= rem
#define DP_STEP_G(C4, R) do {                                               \
        float4 c = (C4);                                                    \
        float p1 = SHFL_UP1(v1_3);                                          \
        float p2 = p1_prev;                                                 \
        float n0 = c.x + fminf(p2,   fminf(v1_0, p1)   + WPV);              \
        float n1 = c.y + fminf(v2_0, fminf(v1_1, v1_0) + WPV);              \
        float n2 = c.z + fminf(v2_1, fminf(v1_2, v1_1) + WPV);              \
        float n3 = c.w + fminf(v2_2, fminf(v1_3, v1_2) + WPV);              \
        if ((R) <= rem) {                                                   \
            p1_prev = p1;                                                   \
            v2_0 = v1_0; v2_1 = v1_1; v2_2 = v1_2; v2_3 = v1_3;             \
            v1_0 = n0;   v1_1 = n1;   v1_2 = n2;   v1_3 = n3;               \
        }                                                                   \
    } while (0)

#define WAIT_BLK(K) do {                                                    \
        while (__hip_atomic_load(&prod_cnt, __ATOMIC_ACQUIRE,               \
                                 __HIP_MEMORY_SCOPE_WORKGROUP) < (K) + 1)   \
            __builtin_amdgcn_s_sleep(1);                                    \
    } while (0)

#define READ_BLK(K)                                                         \
        const char* slot = ring + ((K) % NSLOT) * SLOT_BYTES;               \
        const float4* rp = (const float4*)(slot + (L << 4));                \
        float4 c0  = rp[0 * 64],  c1  = rp[1 * 64],  c2  = rp[2 * 64],  c3  = rp[3 * 64];  \
        float4 c4_ = rp[4 * 64],  c5  = rp[5 * 64],  c6  = rp[6 * 64],  c7  = rp[7 * 64];  \
        float4 c8  = rp[8 * 64],  c9  = rp[9 * 64],  c10 = rp[10 * 64], c11 = rp[11 * 64]; \
        float4 c12 = rp[12 * 64], c13 = rp[13 * 64], c14 = rp[14 * 64], c15 = rp[15 * 64]; \
        __builtin_amdgcn_sched_barrier(0);

    for (int k = 0; k < kLast; ++k) {
        WAIT_BLK(k);
        READ_BLK(k);
        DP_STEP(c0);  DP_STEP(c1);  DP_STEP(c2);  DP_STEP(c3);
        DP_STEP(c4_); DP_STEP(c5);  DP_STEP(c6);  DP_STEP(c7);
        DP_STEP(c8);  DP_STEP(c9);  DP_STEP(c10); DP_STEP(c11);
        DP_STEP(c12); DP_STEP(c13); DP_STEP(c14); DP_STEP(c15);
        if (L == 0)
            __hip_atomic_store(&cons_cnt, k + 1, __ATOMIC_RELEASE,
                               __HIP_MEMORY_SCOPE_WORKGROUP);
    }

    {   // final block: steps 16*kLast .. dEnd
        const int rem = dEnd & 15;
        WAIT_BLK(kLast);
        READ_BLK(kLast);
        DP_STEP_G(c0, 0);   DP_STEP_G(c1, 1);   DP_STEP_G(c2, 2);   DP_STEP_G(c3, 3);
        DP_STEP_G(c4_, 4);  DP_STEP_G(c5, 5);   DP_STEP_G(c6, 6);   DP_STEP_G(c7, 7);
        DP_STEP_G(c8, 8);   DP_STEP_G(c9, 9);   DP_STEP_G(c10, 10); DP_STEP_G(c11, 11);
        DP_STEP_G(c12, 12); DP_STEP_G(c13, 13); DP_STEP_G(c14, 14); DP_STEP_G(c15, 15);
    }

    // loss_i = row dEnd at column la -> t = la-1, lane (la-1)>>2, slot (la-1)&3
    const int tcap = la - 1;
    if (L == (tcap >> 2)) {
        const int k = tcap & 3;
        float r = v1_0;
        if (k == 1) r = v1_1;
        else if (k == 2) r = v1_2;
        else if (k == 3) r = v1_3;
        atomicAdd(out, r);                   // d_out zeroed via hipMemsetAsync
    }
#undef READ_BLK
#undef WAIT_BLK
#undef DP_STEP_G
#undef DP_STEP
#undef SHFL_UP1
}

extern "C" void kernel_launch(void* const* d_in, const int* in_sizes, int n_in,
                              void* d_out, int out_size, void* d_ws, size_t ws_size,
                              hipStream_t stream) {
    const float* feaA = (const float*)d_in[0];
    const int*   lenA = (const int*)d_in[1];
    const float* feaB = (const float*)d_in[2];
    const int*   lenB = (const int*)d_in[3];

    float* sk = (float*)d_ws;                                   // 8*1279*256*4 B

    hipMemsetAsync(d_out, 0, sizeof(float), stream);
    cost_kernel<<<dim3(T1N / 64, (DN + 63) / 64, BATCH), 256, 0, stream>>>(feaA, feaB, lenA, lenB, sk);
    dp_wave_kernel<<<BATCH, 128, 0, stream>>>(sk, lenA, lenB, (float*)d_out);
}